// Round 18
// baseline (290.595 us; speedup 1.0000x reference)
//
#include <hip/hip_runtime.h>

// Problem constants (z: [4, 64, 32, 32, 32] f32, embedding: [1024, 64] f32)
#define CH     64
#define KC     1024
#define SP     32768              // 32*32*32
#define NBATCH 4
#define NTOK   (NBATCH * SP)      // 131072
#define MTOK   64                 // tokens per tile
#define SZZ    68                 // zl row stride (floats)
#define NBLK   256                // persistent blocks: 1 per CU (160 KB LDS each)
#define TILES  (NTOK / MTOK / NBLK)  // 8 tiles per block
#define CAP    16                 // MUST be 16 (R10/R11 A/B: CAP<=8 -> serial full-scan poison)
#define MARGIN 3.0f               // > 2*eps, eps = max |d_bf16 - d_fp32| (~0.9)

// dynamic LDS carve (bytes)
#define OFF_EBL   0               // ushort[1024*64]  131072 B (whole bf16 table)
#define OFF_ZL    131072          // float[64*68]      17408 B
#define OFF_ENL   148480          // float[1024]        4096 B (whole enorm)
#define OFF_RBEST 152576          // float[4][64]       1024 B
#define OFF_RBI   153600          // int[4][64]         1024 B
#define OFF_CAND  154624          // int[64][16]        4096 B (zs-aliased at tail)
#define OFF_CCNT  158720          // int[64]             256 B
#define OFF_FI    158976          // int[64]             256 B
#define SMEM_BYTES 159232         // <= 163840 (160 KiB/CU)

// d_out flat layout (all float32): z_q, loss, perplexity, indices, mean(dist)
#define OFF_ZQ   0
#define OFF_LOSS (NBATCH * CH * SP)      // 8388608
#define OFF_PERP (OFF_LOSS + 1)
#define OFF_IDX  (OFF_PERP + 1)          // 8388610
#define OFF_MEAN (OFF_IDX + NTOK)        // 8519682

// workspace layout (32-bit words)
// [0,1024)      int   hist
// [1024]        float sum_z2
// [1025]        float sum_e2
// [1026,1090)   float sum_zc[64]
// [1090,1154)   float sum_ec[64]
// [1154,2178)   float enorm[1024]
// [4096,20480)  ushort eb[1024*64]  (bf16 embedding table, 128 KB)

typedef __attribute__((ext_vector_type(8))) short  s16x8;   // 8 bf16 (4 VGPRs)
typedef __attribute__((ext_vector_type(4))) float  f32x4;

__device__ __forceinline__ unsigned short f2bf(float f) {   // RNE, deterministic
    unsigned int u = __float_as_uint(f);
    return (unsigned short)((u + 0x7fffu + ((u >> 16) & 1u)) >> 16);
}

// frozen exact fp32 distance (bitwise identical to round 0)
__device__ __forceinline__ float exact_dist(const float* zrow,
                                            const float* __restrict__ emb,
                                            const float* __restrict__ enl, int c) {
    const float4* er = (const float4*)(emb + (size_t)c * CH);
    float a0 = 0.f, a1 = 0.f, a2 = 0.f, a3 = 0.f;
#pragma unroll
    for (int j = 0; j < 16; ++j) {
        float4 e4 = er[j];
        a0 = fmaf(zrow[4 * j + 0], e4.x, a0);
        a1 = fmaf(zrow[4 * j + 1], e4.y, a1);
        a2 = fmaf(zrow[4 * j + 2], e4.z, a2);
        a3 = fmaf(zrow[4 * j + 3], e4.w, a3);
    }
    return enl[c] - 2.f * ((a0 + a1) + (a2 + a3));
}

// prep: blocks 0-3 enorm, block 4 col-stats + zero sums, 5-8 zero hist,
// 9-12 fp32->bf16 embedding table. (unchanged)
__global__ __launch_bounds__(256) void prep(const float* __restrict__ e,
                                            int* __restrict__ hist,
                                            float* __restrict__ sums,
                                            float* __restrict__ sum_zc,
                                            float* __restrict__ sum_ec,
                                            float* __restrict__ enorm,
                                            unsigned short* __restrict__ eb) {
    const int tid = threadIdx.x;
    const int bk = blockIdx.x;
    if (bk < 4) {
        int k = bk * 256 + tid;
        const float4* row = (const float4*)(e + (size_t)k * CH);
        float n = 0.f;
#pragma unroll
        for (int j = 0; j < CH / 4; ++j) {
            float4 v = row[j];
            n += v.x * v.x + v.y * v.y + v.z * v.z + v.w * v.w;
        }
        enorm[k] = n;
    } else if (bk == 4) {
        if (tid == 0) sums[0] = 0.f;
        if (tid < 64) sum_zc[tid] = 0.f;
        __shared__ float ls1[256];
        __shared__ float r2[4];
        int c = tid & 63;
        int strip = tid >> 6;
        float s1 = 0.f, s2 = 0.f;
        for (int k = strip * 256; k < strip * 256 + 256; ++k) {
            float v = e[k * CH + c];
            s1 += v;
            s2 = fmaf(v, v, s2);
        }
        ls1[tid] = s1;
        for (int off = 32; off; off >>= 1) s2 += __shfl_down(s2, off);
        if ((tid & 63) == 0) r2[tid >> 6] = s2;
        __syncthreads();
        if (strip == 0) sum_ec[c] = ls1[c] + ls1[64 + c] + ls1[128 + c] + ls1[192 + c];
        if (tid == 0) sums[1] = r2[0] + r2[1] + r2[2] + r2[3];
    } else if (bk < 9) {
        hist[(bk - 5) * 256 + tid] = 0;
    } else {
        int base = (bk - 9) * 16384;
        for (int j = 0; j < 64; ++j) {
            int i = base + tid + j * 256;
            eb[i] = f2bf(e[i]);
        }
    }
}

// async global->LDS, 16 B per lane, linear wave dest. R4/R13-verified.
#define GLD16(gsrc, ldst)                                                        \
    __builtin_amdgcn_global_load_lds(                                            \
        (const __attribute__((address_space(1))) unsigned int*)(gsrc),           \
        (__attribute__((address_space(3))) unsigned int*)(ldst), 16, 0, 0)

// main: WHOLE-TABLE-RESIDENT persistent kernel. 256 blocks (1/CU), each stages
// the full 128 KB bf16 table + 4 KB enorm into LDS ONCE (R13-verified GLD
// swizzle), then processes 8 token-tiles with ZERO staging/barriers inside the
// two passes (thr is wave-local, R12-verified). Pass-1 code order is globally
// ascending -> bmin chain bitwise identical to R13/R17; candidate membership
// identical; (d,c) lexicographic selection is order-independent -> identical
// output. Rejected alternatives: dbuf (R15/R16 regress), read-quartering (R14
// null), MTOK=128 (R11). LDS = 159232 B dynamic -> 1 block/CU, 4 waves.
__global__ __launch_bounds__(256) void vq_main(const float* __restrict__ z,
                                               const float* __restrict__ emb,
                                               const unsigned short* __restrict__ eb,
                                               const float* __restrict__ enorm,
                                               float* __restrict__ out,
                                               int* __restrict__ hist,
                                               float* __restrict__ sums,
                                               float* __restrict__ sum_zc) {
    extern __shared__ __align__(16) char smem[];
    unsigned short* ebl = (unsigned short*)(smem + OFF_EBL);   // whole table, swizzled
    float* zl   = (float*)(smem + OFF_ZL);
    float* enl  = (float*)(smem + OFF_ENL);
    float* rbest = (float*)(smem + OFF_RBEST);                 // [4][64]
    int*   rbi   = (int*)(smem + OFF_RBI);                     // [4][64]
    int (*cand)[CAP] = (int (*)[CAP])(smem + OFF_CAND);
    int*   ccnt = (int*)(smem + OFF_CCNT);
    int*   fi   = (int*)(smem + OFF_FI);

    const int tid = threadIdx.x;
    const int w = tid >> 6;             // wave 0..3
    const int lane = tid & 63;
    const int n15 = lane & 15;
    const int q = lane >> 4;            // 0..3
    const int gsw = q ^ (n15 & 7);      // swizzled read granule (row&7 == n15&7)

    // ---- stage WHOLE table once: wave w covers rows [w*256, w*256+256),
    //      32 windows of 8 rows. Linear LDS dest (base + lane*16); source row
    //      +(l>>3), source granule (l&7)^(l>>3) (R13-verified, rule #21). ----
    {
        const int l3 = lane >> 3, l7 = lane & 7;
        const size_t gofs = (size_t)((l7 ^ l3) << 3);          // shorts
        for (int it = 0; it < 32; ++it) {
            const unsigned short* gs =
                eb + (size_t)((w << 8) + it * 8 + l3) * CH + gofs;
            GLD16(gs, (char*)ebl + (w << 15) + (it << 10));
        }
#pragma unroll
        for (int j = 0; j < 4; ++j) enl[tid + j * 256] = enorm[tid + j * 256];
    }

    // ---- 8 token-tiles per block (grid-stride), table stays resident ----
    for (int tile = 0; tile < TILES; ++tile) {
        const int t0 = (blockIdx.x + (tile << 8)) * MTOK;   // tile index * 64
        const int bb = t0 >> 15;
        const int s0 = t0 & (SP - 1);

        // ---- stage z tile token-major + ccnt (R17 text) ----
        {
            const float* zbase = z + ((size_t)bb * CH) * SP + s0;
#pragma unroll
            for (int j = 0; j < 4; ++j) {
                int idx = tid + j * 256;        // 0..1023
                int c = idx >> 4;
                int tq = idx & 15;
                float4 v = *(const float4*)(zbase + (size_t)c * SP + tq * 4);
                zl[(4 * tq + 0) * SZZ + c] = v.x;
                zl[(4 * tq + 1) * SZZ + c] = v.y;
                zl[(4 * tq + 2) * SZZ + c] = v.z;
                zl[(4 * tq + 3) * SZZ + c] = v.w;
            }
            if (tid < MTOK) ccnt[tid] = 0;
        }
        __syncthreads();   // zl ready (tile 0: also drains table GLD + enl)

        // ---- persistent A fragments (R8/R12/R13 layout, verified) ----
        s16x8 A0, A1;
        {
            const float* zrow = &zl[(w * 16 + n15) * SZZ];
            float4 za = *(const float4*)(zrow + q * 8);
            float4 zb = *(const float4*)(zrow + q * 8 + 4);
            float4 zc = *(const float4*)(zrow + 32 + q * 8);
            float4 zd = *(const float4*)(zrow + 32 + q * 8 + 4);
            A0[0] = (short)f2bf(za.x); A0[1] = (short)f2bf(za.y);
            A0[2] = (short)f2bf(za.z); A0[3] = (short)f2bf(za.w);
            A0[4] = (short)f2bf(zb.x); A0[5] = (short)f2bf(zb.y);
            A0[6] = (short)f2bf(zb.z); A0[7] = (short)f2bf(zb.w);
            A1[0] = (short)f2bf(zc.x); A1[1] = (short)f2bf(zc.y);
            A1[2] = (short)f2bf(zc.z); A1[3] = (short)f2bf(zc.w);
            A1[4] = (short)f2bf(zd.x); A1[5] = (short)f2bf(zd.y);
            A1[6] = (short)f2bf(zd.z); A1[7] = (short)f2bf(zd.w);
        }

        // ---- pass 1: all 1024 codes from resident LDS, NO barriers.
        //      Ascending code order -> bmin fminf chain bitwise identical ----
        float bmin[4] = {3.4e38f, 3.4e38f, 3.4e38f, 3.4e38f};
        for (int ct = 0; ct < KC / 16; ++ct) {
            const s16x8* rowp = (const s16x8*)&ebl[(size_t)(ct * 16 + n15) << 6];
            s16x8 B0 = rowp[gsw];
            s16x8 B1 = rowp[gsw ^ 4];
            f32x4 acc = {0.f, 0.f, 0.f, 0.f};
            acc = __builtin_amdgcn_mfma_f32_16x16x32_bf16(A0, B0, acc, 0, 0, 0);
            acc = __builtin_amdgcn_mfma_f32_16x16x32_bf16(A1, B1, acc, 0, 0, 0);
            float en = enl[ct * 16 + n15];
#pragma unroll
            for (int r = 0; r < 4; ++r) {
                float d = fmaf(-2.f, acc[r], en);
                bmin[r] = fminf(bmin[r], d);
            }
        }
        // butterfly over n15: min in all 16 lanes (R12-verified) -> wave-local thr
#pragma unroll
        for (int off = 1; off < 16; off <<= 1)
#pragma unroll
            for (int r = 0; r < 4; ++r)
                bmin[r] = fminf(bmin[r], __shfl_xor(bmin[r], off));
        float thr[4];
#pragma unroll
        for (int r = 0; r < 4; ++r) thr[r] = bmin[r] + MARGIN;

        // ---- pass 2: identical compute, collect candidates, NO staging ----
        for (int ct = 0; ct < KC / 16; ++ct) {
            const s16x8* rowp = (const s16x8*)&ebl[(size_t)(ct * 16 + n15) << 6];
            s16x8 B0 = rowp[gsw];
            s16x8 B1 = rowp[gsw ^ 4];
            f32x4 acc = {0.f, 0.f, 0.f, 0.f};
            acc = __builtin_amdgcn_mfma_f32_16x16x32_bf16(A0, B0, acc, 0, 0, 0);
            acc = __builtin_amdgcn_mfma_f32_16x16x32_bf16(A1, B1, acc, 0, 0, 0);
            float en = enl[ct * 16 + n15];
            int code = ct * 16 + n15;
#pragma unroll
            for (int r = 0; r < 4; ++r) {
                float d = fmaf(-2.f, acc[r], en);
                if (d <= thr[r]) {
                    int t = w * 16 + 4 * q + r;
                    int pos = atomicAdd(&ccnt[t], 1);
                    if (pos < CAP) cand[t][pos] = code;
                }
            }
        }
        __syncthreads();   // cand/ccnt visible

        // ---- exact fp32 rescore, 4x-parallel (R13-verified; enl == enorm) ----
        {
            const int t = tid & 63;
            const int part = tid >> 6;
            const float* zrow = &zl[t * SZZ];
            int cnt = ccnt[t];
            float best = 3.4e38f;
            int bi = 0;
            if (cnt <= CAP) {
                for (int j = part; j < cnt; j += 4) {
                    int c = cand[t][j];
                    float d = exact_dist(zrow, emb, enl, c);
                    if (d < best || (d == best && c < bi)) { best = d; bi = c; }
                }
            } else {   // overflow fallback (rare at CAP=16): strided exact scan
                for (int c = part; c < KC; c += 4) {
                    float d = exact_dist(zrow, emb, enl, c);
                    if (d < best || (d == best && c < bi)) { best = d; bi = c; }
                }
            }
            rbest[part * MTOK + t] = best;
            rbi[part * MTOK + t] = bi;
        }
        __syncthreads();
        if (tid < MTOK) {
            float best = rbest[tid];
            int bi = rbi[tid];
#pragma unroll
            for (int p = 1; p < 4; ++p) {
                float b = rbest[p * MTOK + tid];
                int i = rbi[p * MTOK + tid];
                if (b < best || (b == best && i < bi)) { best = b; bi = i; }
            }
            fi[tid] = bi;
            out[OFF_IDX + t0 + tid] = (float)bi;   // coalesced
            atomicAdd(&hist[bi], 1);
        }
        __syncthreads();

        // ---- z_q epilogue: z + (e[code] - z), coalesced per channel ----
#pragma unroll
        for (int j = 0; j < 16; ++j) {
            int idx = tid + j * 256;   // 0..4095
            int c = idx >> 6;
            int t = idx & 63;
            int code = fi[t];
            float ev = emb[(size_t)code * CH + c];   // L1/L2-hot gather
            float zv = zl[t * SZZ + c];
            out[OFF_ZQ + ((size_t)bb * CH + c) * SP + s0 + t] = zv + (ev - zv);
        }

        // ---- z statistics (zs aliased onto dead cand, R12/R13-verified) ----
        {
            float* zs1 = reinterpret_cast<float*>(cand);   // 2048 B <= 4096 B
            float* zs2 = zs1 + 256;
            int c = tid >> 2, qq = tid & 3;
            float s1 = 0.f, s2 = 0.f;
            for (int tt = 0; tt < 16; ++tt) {
                float v = zl[(qq * 16 + tt) * SZZ + c];
                s1 += v;
                s2 = fmaf(v, v, s2);
            }
            zs1[tid] = s1;
            zs2[tid] = s2;
            __syncthreads();
            if (tid < 64) {
                float a = zs1[4 * tid] + zs1[4 * tid + 1] + zs1[4 * tid + 2] + zs1[4 * tid + 3];
                atomicAdd(&sum_zc[tid], a);
                float bsum = zs2[4 * tid] + zs2[4 * tid + 1] + zs2[4 * tid + 2] + zs2[4 * tid + 3];
                for (int off = 32; off; off >>= 1) bsum += __shfl_down(bsum, off);
                if (tid == 0) atomicAdd(&sums[0], bsum);
            }
        }
        __syncthreads();   // seal zl/zs reads before next tile's overwrite
    }
}

__global__ __launch_bounds__(1024) void finalize(const int* __restrict__ hist,
                                                 const float* __restrict__ sums,
                                                 const float* __restrict__ sum_zc,
                                                 const float* __restrict__ sum_ec,
                                                 float* __restrict__ out) {
    __shared__ float red[1024];
    int k = threadIdx.x;
    float p = (float)hist[k] * (1.0f / (float)NTOK);
    red[k] = p * logf(p + 1e-10f);
    __syncthreads();
    for (int off = 512; off; off >>= 1) {
        if (k < off) red[k] += red[k + off];
        __syncthreads();
    }
    if (k == 0) {
        out[OFF_PERP] = expf(-red[0]);
        out[OFF_LOSS] = 0.f;
        double dot = 0.0;
        for (int c = 0; c < CH; ++c) dot += (double)sum_zc[c] * (double)sum_ec[c];
        double mean = ((double)KC * (double)sums[0] + (double)NTOK * (double)sums[1] - 2.0 * dot)
                      / ((double)NTOK * (double)KC);
        out[OFF_MEAN] = (float)mean;
    }
}

extern "C" void kernel_launch(void* const* d_in, const int* in_sizes, int n_in,
                              void* d_out, int out_size, void* d_ws, size_t ws_size,
                              hipStream_t stream) {
    const float* z   = (const float*)d_in[0];
    const float* emb = (const float*)d_in[1];
    float* out = (float*)d_out;

    int*            hist   = (int*)d_ws;
    float*          sums   = (float*)d_ws + 1024;   // [0]=sum_z2 [1]=sum_e2
    float*          sum_zc = (float*)d_ws + 1026;
    float*          sum_ec = (float*)d_ws + 1090;
    float*          enorm  = (float*)d_ws + 1154;
    unsigned short* eb     = (unsigned short*)((int*)d_ws + 4096);  // 128 KB bf16 table

    // allow 159232 B of dynamic LDS (160 KiB/CU on gfx950; host-side, capture-safe)
    hipFuncSetAttribute(reinterpret_cast<const void*>(&vq_main),
                        hipFuncAttributeMaxDynamicSharedMemorySize, SMEM_BYTES);

    prep<<<13, 256, 0, stream>>>(emb, hist, sums, sum_zc, sum_ec, enorm, eb);
    vq_main<<<NBLK, 256, SMEM_BYTES, stream>>>(z, emb, eb, enorm, out, hist, sums, sum_zc);
    finalize<<<1, 1024, 0, stream>>>(hist, sums, sum_zc, sum_ec, out);
}

// Round 19
// 209.570 us; speedup vs baseline: 1.3866x; 1.3866x over previous
//
#include <hip/hip_runtime.h>

// Problem constants (z: [4, 64, 32, 32, 32] f32, embedding: [1024, 64] f32)
#define CH     64
#define KC     1024
#define SP     32768              // 32*32*32
#define NBATCH 4
#define NTOK   (NBATCH * SP)      // 131072
#define MTOK   64                 // tokens per block (R8/R12-verified; beats MTOK=128 via residency)
#define SZZ    68                 // zl row stride (floats)
#define ECH    128                // codes per LDS chunk (8 chunks, R8/R12-verified)
#define NCHK   (KC / ECH)         // 8
#define CAP    16                 // MUST be 16: CAP<=8 was the session's poison (R10/R11 A/B:
                                  // 537 -> 159 us on the CAP 8->16 flip; overflow routes tokens
                                  // through the serial full-scan fallback)
#define MARGIN 3.0f               // > 2*eps, eps = max |d_bf16 - d_fp32| (~0.9)

// d_out flat layout (all float32): z_q, loss, perplexity, indices, mean(dist)
#define OFF_ZQ   0
#define OFF_LOSS (NBATCH * CH * SP)      // 8388608
#define OFF_PERP (OFF_LOSS + 1)
#define OFF_IDX  (OFF_PERP + 1)          // 8388610
#define OFF_MEAN (OFF_IDX + NTOK)        // 8519682

// workspace layout (32-bit words)
// [0,1024)      int   hist
// [1024]        float sum_z2
// [1025]        float sum_e2
// [1026,1090)   float sum_zc[64]
// [1090,1154)   float sum_ec[64]
// [1154,2178)   float enorm[1024]
// [4096,20480)  ushort eb[1024*64]  (bf16 embedding table, 128 KB)

typedef __attribute__((ext_vector_type(8))) short  s16x8;   // 8 bf16 (4 VGPRs)
typedef __attribute__((ext_vector_type(4))) float  f32x4;

__device__ __forceinline__ unsigned short f2bf(float f) {   // RNE, deterministic
    unsigned int u = __float_as_uint(f);
    return (unsigned short)((u + 0x7fffu + ((u >> 16) & 1u)) >> 16);
}

// frozen exact fp32 distance (bitwise identical to round 0: stride-4
// fmaf chains ascending j, combine nrm - 2*((a0+a1)+(a2+a3)))
__device__ __forceinline__ float exact_dist(const float* zrow,
                                            const float* __restrict__ emb,
                                            const float* __restrict__ enl, int c) {
    const float4* er = (const float4*)(emb + (size_t)c * CH);
    float a0 = 0.f, a1 = 0.f, a2 = 0.f, a3 = 0.f;
#pragma unroll
    for (int j = 0; j < 16; ++j) {
        float4 e4 = er[j];
        a0 = fmaf(zrow[4 * j + 0], e4.x, a0);
        a1 = fmaf(zrow[4 * j + 1], e4.y, a1);
        a2 = fmaf(zrow[4 * j + 2], e4.z, a2);
        a3 = fmaf(zrow[4 * j + 3], e4.w, a3);
    }
    return enl[c] - 2.f * ((a0 + a1) + (a2 + a3));
}

// prep: blocks 0-3 enorm, block 4 col-stats + zero sums, 5-8 zero hist,
// 9-12 fp32->bf16 embedding table. (unchanged)
__global__ __launch_bounds__(256) void prep(const float* __restrict__ e,
                                            int* __restrict__ hist,
                                            float* __restrict__ sums,
                                            float* __restrict__ sum_zc,
                                            float* __restrict__ sum_ec,
                                            float* __restrict__ enorm,
                                            unsigned short* __restrict__ eb) {
    const int tid = threadIdx.x;
    const int bk = blockIdx.x;
    if (bk < 4) {
        int k = bk * 256 + tid;
        const float4* row = (const float4*)(e + (size_t)k * CH);
        float n = 0.f;
#pragma unroll
        for (int j = 0; j < CH / 4; ++j) {
            float4 v = row[j];
            n += v.x * v.x + v.y * v.y + v.z * v.z + v.w * v.w;
        }
        enorm[k] = n;
    } else if (bk == 4) {
        if (tid == 0) sums[0] = 0.f;
        if (tid < 64) sum_zc[tid] = 0.f;
        __shared__ float ls1[256];
        __shared__ float r2[4];
        int c = tid & 63;
        int strip = tid >> 6;
        float s1 = 0.f, s2 = 0.f;
        for (int k = strip * 256; k < strip * 256 + 256; ++k) {
            float v = e[k * CH + c];
            s1 += v;
            s2 = fmaf(v, v, s2);
        }
        ls1[tid] = s1;
        for (int off = 32; off; off >>= 1) s2 += __shfl_down(s2, off);
        if ((tid & 63) == 0) r2[tid >> 6] = s2;
        __syncthreads();
        if (strip == 0) sum_ec[c] = ls1[c] + ls1[64 + c] + ls1[128 + c] + ls1[192 + c];
        if (tid == 0) sums[1] = r2[0] + r2[1] + r2[2] + r2[3];
    } else if (bk < 9) {
        hist[(bk - 5) * 256 + tid] = 0;
    } else {
        int base = (bk - 9) * 16384;
        for (int j = 0; j < 64; ++j) {
            int i = base + tid + j * 256;
            eb[i] = f2bf(e[i]);
        }
    }
}

// async global->LDS, 16 B per lane, linear wave dest. R4/R13-verified.
#define GLD16(gsrc, ldst)                                                        \
    __builtin_amdgcn_global_load_lds(                                            \
        (const __attribute__((address_space(1))) unsigned int*)(gsrc),           \
        (__attribute__((address_space(3))) unsigned int*)(ldst), 16, 0, 0)

// main: the session-best structure (R13/R17, 137.3 us): GLD-staged ebl (linear
// dest, pre-swizzled source granule (l&7)^(l>>3), swizzled reads gsw=q^(n15&7)),
// chunk-local enl, wave-local butterfly threshold, 4x-parallel rescore.
// Probed and rejected: MTOK=128 (residency loss), read-quartering (null),
// double-buffering at ECH=64/128 (regress), whole-table persistent 1 blk/CU
// (regress — inter-block overlap at 4 blocks/CU is what hides all serial
// sections). LDS = 40960 B -> 4 blocks/CU.
__global__ __launch_bounds__(256, 2) void vq_main(const float* __restrict__ z,
                                                  const float* __restrict__ emb,
                                                  const unsigned short* __restrict__ eb,
                                                  const float* __restrict__ enorm,
                                                  float* __restrict__ out,
                                                  int* __restrict__ hist,
                                                  float* __restrict__ sums,
                                                  float* __restrict__ sum_zc) {
    __shared__ float zl[MTOK * SZZ];                        // 17408 B fp32 z, token-major
    __shared__ __align__(16) unsigned short ebl[ECH * 64];  // 16384 B bf16 chunk, swizzled
    __shared__ float enl[ECH];                              // 512 B enorm chunk
    __shared__ int   cand[MTOK][CAP];                       // 4096 B (zs-aliased at tail)
    __shared__ int   ccnt[MTOK];                            // 256 B
    __shared__ int   fi[MTOK];                              // 256 B
    __shared__ float rbest[4][MTOK];                        // 1024 B rescore partials
    __shared__ int   rbi[4][MTOK];                          // 1024 B

    const int tid = threadIdx.x;
    const int w = tid >> 6;             // wave 0..3
    const int lane = tid & 63;
    const int n15 = lane & 15;
    const int q = lane >> 4;            // 0..3
    const int t0 = blockIdx.x * MTOK;   // grid = 2048
    const int bb = t0 >> 15;
    const int s0 = t0 & (SP - 1);

    // ---- GLD staging: wave w covers ebl rows [w*32, w*32+32), 4 windows of
    //      1 KB (8 rows). Lane l -> dest granule lane (linear); source row
    //      +(l>>3), source granule (l&7)^(l>>3) (pre-swizzle; row&7 == l>>3).
    //      Reads undo it with gsw = q^(n15&7).  (rule #21 both-sides; R4) ----
    const int l3 = lane >> 3, l7 = lane & 7;
    const size_t gofs = (size_t)((l7 ^ l3) << 3);           // shorts
#define STAGE(cb)                                                             \
    {                                                                         \
        _Pragma("unroll")                                                     \
        for (int it = 0; it < 4; ++it) {                                      \
            const unsigned short* gs =                                        \
                eb + (size_t)((cb) + (w << 5) + it * 8 + l3) * CH + gofs;     \
            GLD16(gs, (char*)ebl + (w << 12) + (it << 10));                   \
        }                                                                     \
    }

    // ---- stage z tile token-major + ccnt (R12 prologue) ----
    {
        const float* zbase = z + ((size_t)bb * CH) * SP + s0;
#pragma unroll
        for (int j = 0; j < 4; ++j) {
            int idx = tid + j * 256;        // 0..1023
            int c = idx >> 4;
            int tq = idx & 15;
            float4 v = *(const float4*)(zbase + (size_t)c * SP + tq * 4);
            zl[(4 * tq + 0) * SZZ + c] = v.x;
            zl[(4 * tq + 1) * SZZ + c] = v.y;
            zl[(4 * tq + 2) * SZZ + c] = v.z;
            zl[(4 * tq + 3) * SZZ + c] = v.w;
        }
        if (tid < MTOK) ccnt[tid] = 0;
    }
    __syncthreads();

    // ---- build persistent A fragments (R8/R12 layout, verified) ----
    s16x8 A0, A1;
    {
        const float* zrow = &zl[(w * 16 + n15) * SZZ];
        float4 za = *(const float4*)(zrow + q * 8);
        float4 zb = *(const float4*)(zrow + q * 8 + 4);
        float4 zc = *(const float4*)(zrow + 32 + q * 8);
        float4 zd = *(const float4*)(zrow + 32 + q * 8 + 4);
        A0[0] = (short)f2bf(za.x); A0[1] = (short)f2bf(za.y);
        A0[2] = (short)f2bf(za.z); A0[3] = (short)f2bf(za.w);
        A0[4] = (short)f2bf(zb.x); A0[5] = (short)f2bf(zb.y);
        A0[6] = (short)f2bf(zb.z); A0[7] = (short)f2bf(zb.w);
        A1[0] = (short)f2bf(zc.x); A1[1] = (short)f2bf(zc.y);
        A1[2] = (short)f2bf(zc.z); A1[3] = (short)f2bf(zc.w);
        A1[4] = (short)f2bf(zd.x); A1[5] = (short)f2bf(zd.y);
        A1[6] = (short)f2bf(zd.z); A1[7] = (short)f2bf(zd.w);
    }
    const int gsw = q ^ (n15 & 7);     // swizzled read granule (row&7 == n15&7)

    // ---- pass 1: per-token min of d_bf (values only), chunked B in LDS ----
    float bmin[4] = {3.4e38f, 3.4e38f, 3.4e38f, 3.4e38f};
    for (int ch = 0; ch < NCHK; ++ch) {
        __syncthreads();   // prior chunk's ebl/enl reads done
        STAGE(ch * ECH)    // async DMA; drained by the next barrier's vmcnt(0)
        if (tid < ECH) enl[tid] = enorm[ch * ECH + tid];
        __syncthreads();
        for (int ct = 0; ct < ECH / 16; ++ct) {
            const s16x8* rowp = (const s16x8*)&ebl[(size_t)(ct * 16 + n15) << 6];
            s16x8 B0 = rowp[gsw];
            s16x8 B1 = rowp[gsw ^ 4];
            f32x4 acc = {0.f, 0.f, 0.f, 0.f};
            acc = __builtin_amdgcn_mfma_f32_16x16x32_bf16(A0, B0, acc, 0, 0, 0);
            acc = __builtin_amdgcn_mfma_f32_16x16x32_bf16(A1, B1, acc, 0, 0, 0);
            float en = enl[ct * 16 + n15];
#pragma unroll
            for (int r = 0; r < 4; ++r) {
                float d = fmaf(-2.f, acc[r], en);
                bmin[r] = fminf(bmin[r], d);
            }
        }
    }
    // butterfly over n15: min lands in all 16 lanes (R12-verified) ->
    // threshold wave-local, no dmin_l, no extra barrier
#pragma unroll
    for (int off = 1; off < 16; off <<= 1)
#pragma unroll
        for (int r = 0; r < 4; ++r)
            bmin[r] = fminf(bmin[r], __shfl_xor(bmin[r], off));
    float thr[4];
#pragma unroll
    for (int r = 0; r < 4; ++r) thr[r] = bmin[r] + MARGIN;

    // ---- pass 2: identical compute, collect candidates within margin.
    //      chunk order 7,0..6: chunk 7 (ebl+enl) still resident -> no restage ----
    for (int cc = 0; cc < NCHK; ++cc) {
        int ch = (cc == 0) ? (NCHK - 1) : (cc - 1);
        if (cc) {
            __syncthreads();
            STAGE(ch * ECH)
            if (tid < ECH) enl[tid] = enorm[ch * ECH + tid];
            __syncthreads();
        }
        for (int ct = 0; ct < ECH / 16; ++ct) {
            const s16x8* rowp = (const s16x8*)&ebl[(size_t)(ct * 16 + n15) << 6];
            s16x8 B0 = rowp[gsw];
            s16x8 B1 = rowp[gsw ^ 4];
            f32x4 acc = {0.f, 0.f, 0.f, 0.f};
            acc = __builtin_amdgcn_mfma_f32_16x16x32_bf16(A0, B0, acc, 0, 0, 0);
            acc = __builtin_amdgcn_mfma_f32_16x16x32_bf16(A1, B1, acc, 0, 0, 0);
            float en = enl[ct * 16 + n15];
#pragma unroll
            for (int r = 0; r < 4; ++r) {
                float d = fmaf(-2.f, acc[r], en);
                if (d <= thr[r]) {
                    int t = w * 16 + 4 * q + r;
                    int pos = atomicAdd(&ccnt[t], 1);
                    if (pos < CAP) cand[t][pos] = ch * ECH + ct * 16 + n15;
                }
            }
        }
    }
    __syncthreads();

    // ---- exact fp32 rescore, 4x-parallel: token t = tid&63, part = tid>>6
    //      takes candidates j = part, part+4, ... Per-candidate arithmetic is
    //      byte-identical; lexicographic (d,c) min over the set is evaluation-
    //      order-independent -> result identical to the serial loop. ----
    {
        const int t = tid & 63;
        const int part = tid >> 6;
        const float* zrow = &zl[t * SZZ];
        int cnt = ccnt[t];
        float best = 3.4e38f;
        int bi = 0;
        if (cnt <= CAP) {
            for (int j = part; j < cnt; j += 4) {
                int c = cand[t][j];
                float d = exact_dist(zrow, emb, enorm, c);
                if (d < best || (d == best && c < bi)) { best = d; bi = c; }
            }
        } else {   // overflow fallback (rare at CAP=16): strided exact scan
            for (int c = part; c < KC; c += 4) {
                float d = exact_dist(zrow, emb, enorm, c);
                if (d < best || (d == best && c < bi)) { best = d; bi = c; }
            }
        }
        rbest[part][t] = best;
        rbi[part][t] = bi;
    }
    __syncthreads();
    if (tid < MTOK) {
        float best = rbest[0][tid];
        int bi = rbi[0][tid];
#pragma unroll
        for (int p = 1; p < 4; ++p) {
            float b = rbest[p][tid];
            int i = rbi[p][tid];
            if (b < best || (b == best && i < bi)) { best = b; bi = i; }
        }
        fi[tid] = bi;
        out[OFF_IDX + t0 + tid] = (float)bi;   // coalesced
        atomicAdd(&hist[bi], 1);
    }
    __syncthreads();

    // ---- z_q epilogue: z + (e[code] - z), coalesced per channel ----
#pragma unroll
    for (int j = 0; j < 16; ++j) {
        int idx = tid + j * 256;   // 0..4095
        int c = idx >> 6;
        int t = idx & 63;
        int code = fi[t];
        float ev = emb[(size_t)code * CH + c];   // L1/L2-hot gather
        float zv = zl[t * SZZ + c];
        out[OFF_ZQ + ((size_t)bb * CH + c) * SP + s0 + t] = zv + (ev - zv);
    }

    // ---- z statistics at kernel tail (zs aliased onto dead cand, R12) ----
    {
        float* zs1 = reinterpret_cast<float*>(cand);   // 2048 B needed <= 4096 B
        float* zs2 = zs1 + 256;
        int c = tid >> 2, qq = tid & 3;
        float s1 = 0.f, s2 = 0.f;
        for (int tt = 0; tt < 16; ++tt) {
            float v = zl[(qq * 16 + tt) * SZZ + c];
            s1 += v;
            s2 = fmaf(v, v, s2);
        }
        zs1[tid] = s1;
        zs2[tid] = s2;
        __syncthreads();
        if (tid < 64) {
            float a = zs1[4 * tid] + zs1[4 * tid + 1] + zs1[4 * tid + 2] + zs1[4 * tid + 3];
            atomicAdd(&sum_zc[tid], a);
            float bsum = zs2[4 * tid] + zs2[4 * tid + 1] + zs2[4 * tid + 2] + zs2[4 * tid + 3];
            for (int off = 32; off; off >>= 1) bsum += __shfl_down(bsum, off);
            if (tid == 0) atomicAdd(&sums[0], bsum);
        }
    }
#undef STAGE
}

__global__ __launch_bounds__(1024) void finalize(const int* __restrict__ hist,
                                                 const float* __restrict__ sums,
                                                 const float* __restrict__ sum_zc,
                                                 const float* __restrict__ sum_ec,
                                                 float* __restrict__ out) {
    __shared__ float red[1024];
    int k = threadIdx.x;
    float p = (float)hist[k] * (1.0f / (float)NTOK);
    red[k] = p * logf(p + 1e-10f);
    __syncthreads();
    for (int off = 512; off; off >>= 1) {
        if (k < off) red[k] += red[k + off];
        __syncthreads();
    }
    if (k == 0) {
        out[OFF_PERP] = expf(-red[0]);
        out[OFF_LOSS] = 0.f;
        double dot = 0.0;
        for (int c = 0; c < CH; ++c) dot += (double)sum_zc[c] * (double)sum_ec[c];
        double mean = ((double)KC * (double)sums[0] + (double)NTOK * (double)sums[1] - 2.0 * dot)
                      / ((double)NTOK * (double)KC);
        out[OFF_MEAN] = (float)mean;
    }
}

extern "C" void kernel_launch(void* const* d_in, const int* in_sizes, int n_in,
                              void* d_out, int out_size, void* d_ws, size_t ws_size,
                              hipStream_t stream) {
    const float* z   = (const float*)d_in[0];
    const float* emb = (const float*)d_in[1];
    float* out = (float*)d_out;

    int*            hist   = (int*)d_ws;
    float*          sums   = (float*)d_ws + 1024;   // [0]=sum_z2 [1]=sum_e2
    float*          sum_zc = (float*)d_ws + 1026;
    float*          sum_ec = (float*)d_ws + 1090;
    float*          enorm  = (float*)d_ws + 1154;
    unsigned short* eb     = (unsigned short*)((int*)d_ws + 4096);  // 128 KB bf16 table

    prep<<<13, 256, 0, stream>>>(emb, hist, sums, sum_zc, sum_ec, enorm, eb);
    vq_main<<<NTOK / MTOK, 256, 0, stream>>>(z, emb, eb, enorm, out, hist, sums, sum_zc);
    finalize<<<1, 1024, 0, stream>>>(hist, sums, sum_zc, sum_ec, out);
}